// Round 1
// baseline (235.501 us; speedup 1.0000x reference)
//
#include <hip/hip_runtime.h>

typedef __attribute__((ext_vector_type(4))) float f32x4;
typedef __attribute__((ext_vector_type(8))) _Float16 f16x8;

#define D 256          // D_in == D_out == 256
#define VBS 128        // ghost batch rows per chunk
#define BN_EPS 1e-5f

// Pack W[k][n] (f32, row-major 256x256) into f16 MFMA B-fragment order:
// wp[((kb*16+ct)*64 + lane)*8 + j] = W[kb*32 + (lane>>4)*8 + j][ct*16 + (lane&15)]
__global__ void pack_w_kernel(const float* __restrict__ W, _Float16* __restrict__ wp) {
    int idx = blockIdx.x * blockDim.x + threadIdx.x;   // [0, 8192)
    int kb  = idx >> 10;          // 8 k-blocks of 32
    int rem = idx & 1023;
    int ct  = rem >> 6;           // 16 col-tiles of 16
    int l   = rem & 63;           // lane
    int col = ct * 16 + (l & 15);
    int k0  = kb * 32 + ((l >> 4) << 3);
    f16x8 v;
#pragma unroll
    for (int j = 0; j < 8; ++j) v[j] = (_Float16)W[(k0 + j) * D + col];
    *reinterpret_cast<f16x8*>(wp + (size_t)idx * 8) = v;
}

// One block per BN chunk of 128 rows. 4 waves; each wave computes 32 rows x 256 cols.
__global__ __launch_bounds__(256, 2)
void fused_kernel(const float* __restrict__ A, const float* __restrict__ priors,
                  const _Float16* __restrict__ Wp, const float* __restrict__ gamma,
                  const float* __restrict__ beta, float* __restrict__ out) {
    const int chunk = blockIdx.x;
    const int tid   = threadIdx.x;
    const int wave  = tid >> 6;
    const int lane  = tid & 63;
    const int lrow  = lane & 15;   // A-row within 16x16 tile / D-col within tile
    const int lgrp  = lane >> 4;   // k-group in frags / row-group in C

    const int row0 = chunk * VBS + wave * 32;

    f32x4 acc[2][16];
#pragma unroll
    for (int rt = 0; rt < 2; ++rt)
#pragma unroll
        for (int ct = 0; ct < 16; ++ct) {
            f32x4 z = {0.f, 0.f, 0.f, 0.f};
            acc[rt][ct] = z;
        }

    const float* a0 = A + (size_t)(row0 + lrow) * D + lgrp * 8;

    // ---- GEMM: h = a @ W (K = 256 in 8 steps of 32) ----
#pragma unroll
    for (int kb = 0; kb < 8; ++kb) {
        f16x8 af[2];
#pragma unroll
        for (int rt = 0; rt < 2; ++rt) {
            const float* ap = a0 + rt * 16 * D + kb * 32;
            f32x4 lo = *reinterpret_cast<const f32x4*>(ap);
            f32x4 hi = *reinterpret_cast<const f32x4*>(ap + 4);
            f16x8 t;
            t[0] = (_Float16)lo[0]; t[1] = (_Float16)lo[1];
            t[2] = (_Float16)lo[2]; t[3] = (_Float16)lo[3];
            t[4] = (_Float16)hi[0]; t[5] = (_Float16)hi[1];
            t[6] = (_Float16)hi[2]; t[7] = (_Float16)hi[3];
            af[rt] = t;
        }
        const f16x8* wpp = reinterpret_cast<const f16x8*>(Wp) + (kb * 16) * 64 + lane;
#pragma unroll
        for (int ct = 0; ct < 16; ++ct) {
            f16x8 bf = wpp[ct * 64];
            acc[0][ct] = __builtin_amdgcn_mfma_f32_16x16x32_f16(af[0], bf, acc[0][ct], 0, 0, 0);
            acc[1][ct] = __builtin_amdgcn_mfma_f32_16x16x32_f16(af[1], bf, acc[1][ct], 0, 0, 0);
        }
    }

    // ---- Ghost BN stats: per-column mean/var over the block's 128 rows ----
    __shared__ float sSum[4][D];
    __shared__ float sSq[4][D];
#pragma unroll
    for (int ct = 0; ct < 16; ++ct) {
        float s = 0.f, q = 0.f;
#pragma unroll
        for (int rt = 0; rt < 2; ++rt)
#pragma unroll
            for (int r = 0; r < 4; ++r) {
                float v = acc[rt][ct][r];
                s += v; q += v * v;
            }
        s += __shfl_xor(s, 16); q += __shfl_xor(q, 16);
        s += __shfl_xor(s, 32); q += __shfl_xor(q, 32);
        if (lgrp == 0) { sSum[wave][ct * 16 + lrow] = s; sSq[wave][ct * 16 + lrow] = q; }
    }
    __syncthreads();

    __shared__ float sA[D], sB[D];
    {
        int c = tid;  // 256 threads, one column each
        float s = sSum[0][c] + sSum[1][c] + sSum[2][c] + sSum[3][c];
        float q = sSq[0][c] + sSq[1][c] + sSq[2][c] + sSq[3][c];
        float mean = s * (1.0f / 128.0f);
        float var  = q * (1.0f / 128.0f) - mean * mean;
        float rstd = rsqrtf(var + BN_EPS);
        float g    = gamma[c] * rstd;
        sA[c] = g;
        sB[c] = beta[c] - mean * g;
    }
    __syncthreads();

    float colA[16], colB[16];
#pragma unroll
    for (int ct = 0; ct < 16; ++ct) {
        colA[ct] = sA[ct * 16 + lrow];
        colB[ct] = sB[ct * 16 + lrow];
    }

    // ---- per-row: BN apply, * priors, sparsemax (Michelot fixed-point) ----
#pragma unroll
    for (int rt = 0; rt < 2; ++rt) {
#pragma unroll
        for (int r = 0; r < 4; ++r) {
            const int row = row0 + rt * 16 + lgrp * 4 + r;
            const float* pr = priors + (size_t)row * D + lrow;
            float z[16];
            float m = -1e30f;
#pragma unroll
            for (int ct = 0; ct < 16; ++ct) {
                float x = acc[rt][ct][r] * colA[ct] + colB[ct];
                x *= pr[ct * 16];
                z[ct] = x;
                m = fmaxf(m, x);
            }
#pragma unroll
            for (int o = 8; o >= 1; o >>= 1) m = fmaxf(m, __shfl_xor(m, o));
#pragma unroll
            for (int ct = 0; ct < 16; ++ct) z[ct] -= m;

            // tau: root of  sum(relu(z - tau)) = 1.   tau0 = -1 guarantees f >= 0.
            float tau = -1.0f;
            for (int it = 0; it < 24; ++it) {
                float s = 0.f, c = 0.f;
#pragma unroll
                for (int ct = 0; ct < 16; ++ct) {
                    bool act = z[ct] > tau;
                    s += act ? z[ct] : 0.f;
                    c += act ? 1.f : 0.f;
                }
#pragma unroll
                for (int o = 8; o >= 1; o >>= 1) {
                    s += __shfl_xor(s, o);
                    c += __shfl_xor(c, o);
                }
                float taun = (s - 1.0f) / c;
                if (taun <= tau) break;
                tau = taun;
            }

            float* op = out + (size_t)row * D + lrow;
#pragma unroll
            for (int ct = 0; ct < 16; ++ct) op[ct * 16] = fmaxf(z[ct] - tau, 0.f);
        }
    }
}

extern "C" void kernel_launch(void* const* d_in, const int* in_sizes, int n_in,
                              void* d_out, int out_size, void* d_ws, size_t ws_size,
                              hipStream_t stream) {
    const float* a      = (const float*)d_in[0];
    const float* priors = (const float*)d_in[1];
    const float* W      = (const float*)d_in[2];
    // d_in[3] = b : unused — ghost-BN mean subtraction cancels any per-column bias.
    const float* gamma  = (const float*)d_in[4];
    const float* beta   = (const float*)d_in[5];
    float* out = (float*)d_out;
    _Float16* wp = (_Float16*)d_ws;   // 256*256 f16 = 128 KB packed W

    const int B = in_sizes[0] / D;        // 262144
    const int nchunks = B / VBS;          // 2048

    hipLaunchKernelGGL(pack_w_kernel, dim3(32), dim3(256), 0, stream, W, wp);
    hipLaunchKernelGGL(fused_kernel, dim3(nchunks), dim3(256), 0, stream,
                       a, priors, wp, gamma, beta, out);
}